// Round 1
// baseline (1674.558 us; speedup 1.0000x reference)
//
#include <hip/hip_runtime.h>

// Problem constants
#define DI 1536
#define DM 768
#define NS 16
#define RK 48
#define LQ 512
#define BB 2
#define MROWS (BB*LQ)   // 1024

typedef short bf16x8 __attribute__((ext_vector_type(8)));
typedef float f32x4 __attribute__((ext_vector_type(4)));

static __device__ __forceinline__ short f2bf(float f) {
  unsigned u = __float_as_uint(f);
  u += 0x7FFF + ((u >> 16) & 1);   // round-to-nearest-even
  return (short)(u >> 16);
}

// ---------------- embedding gather ----------------
__global__ __launch_bounds__(256) void k_gather(const int* __restrict__ ids,
                                                const int* __restrict__ mask,
                                                const float* __restrict__ embed,
                                                float* __restrict__ h) {
  int row = blockIdx.x;                 // 0..1023 = b*512 + l
  int id = ids[row];
  float mk = (float)mask[row];
  const float* src = embed + (size_t)id * DM;
  float* dst = h + (size_t)row * DM;
  for (int i = threadIdx.x; i < DM; i += 256) dst[i] = src[i] * mk;
}

// ---------------- rmsnorm (768 per row) ----------------
__global__ __launch_bounds__(256) void k_rmsnorm(const float* __restrict__ h,
                                                 const float* __restrict__ w,
                                                 float* __restrict__ out) {
  int row = blockIdx.x;
  const float* x = h + (size_t)row * DM;
  int tid = threadIdx.x;
  float v0 = x[tid], v1 = x[tid + 256], v2 = x[tid + 512];
  float ss = v0*v0 + v1*v1 + v2*v2;
  #pragma unroll
  for (int o = 32; o > 0; o >>= 1) ss += __shfl_xor(ss, o);
  __shared__ float ps[4];
  if ((tid & 63) == 0) ps[tid >> 6] = ss;
  __syncthreads();
  float tot = ps[0] + ps[1] + ps[2] + ps[3];
  float scale = rsqrtf(tot * (1.0f/768.0f) + 1e-5f);
  float* o0 = out + (size_t)row * DM;
  o0[tid]       = v0 * scale * w[tid];
  o0[tid + 256] = v1 * scale * w[tid + 256];
  o0[tid + 512] = v2 * scale * w[tid + 512];
}

// ---------------- bf16 MFMA GEMM: C[m,n] = sum_k A[m,k]*B[n,k] (+C) ----------------
// A: M x K row-major (M multiple of TM*32), B: N x K row-major (N tail OK), C: M x N
// Block remap: panels of GC column-tiles x ALL row-tiles, rows fastest, so every
// co-resident cohort shares one B panel (B fetched once from HBM instead of ~4x).
template<int TM, int TN, bool RES>
__global__ __launch_bounds__(256) void k_gemm_nt(const float* __restrict__ A,
                                                 const float* __restrict__ B,
                                                 float* __restrict__ C,
                                                 int M, int N, int K) {
  constexpr int BM = TM*32, BN = TN*32, BK = 32, SK = 40;  // SK pad: 80B rows, 2-way-only LDS conflicts
  __shared__ short As[BM*SK];
  __shared__ short Bs[BN*SK];

  // ---- locality-aware bijective block remap (panel = GC cols x RT rows) ----
  int bx, by;
  {
    const int GC = 96;                         // 96 cols * 8 rows = 768 blocks ~ resident set
    int CT = gridDim.x, RT = gridDim.y;
    int lin = blockIdx.y * CT + blockIdx.x;    // dispatch order: x fastest
    int panel = GC * RT;
    int grp = lin / panel;
    int rem = lin - grp * panel;
    int c0 = grp * GC;
    int gc = CT - c0; if (gc > GC) gc = GC;    // tail panel: fewer columns, still bijective
    by = rem % RT;                              // rows fastest: 8 readers of a B tile consecutive
    bx = c0 + rem / RT;
  }

  const int m0 = by * BM, n0 = bx * BN;
  const int tid = threadIdx.x;
  const int wave = tid >> 6, lane = tid & 63;
  const int wm = (wave >> 1) * (TM*16), wn = (wave & 1) * (TN*16);
  const int lm = lane & 15, q = lane >> 4;
  const int trow = tid >> 3;          // 0..31
  const int tcol = (tid & 7) * 4;     // 0..28
  f32x4 acc[TM][TN] = {};
  for (int kt = 0; kt < K; kt += BK) {
    float4 av[TM], bv[TN];
    #pragma unroll
    for (int p = 0; p < TM; p++)
      av[p] = *(const float4*)(A + (size_t)(m0 + p*32 + trow)*K + kt + tcol);
    #pragma unroll
    for (int p = 0; p < TN; p++) {
      int bn = n0 + p*32 + trow;
      bv[p] = (bn < N) ? *(const float4*)(B + (size_t)bn*K + kt + tcol)
                       : make_float4(0.f, 0.f, 0.f, 0.f);
    }
    __syncthreads();   // previous iteration's LDS reads done
    #pragma unroll
    for (int p = 0; p < TM; p++) {
      short4 s; s.x = f2bf(av[p].x); s.y = f2bf(av[p].y); s.z = f2bf(av[p].z); s.w = f2bf(av[p].w);
      *(short4*)(&As[(p*32 + trow)*SK + tcol]) = s;
    }
    #pragma unroll
    for (int p = 0; p < TN; p++) {
      short4 s; s.x = f2bf(bv[p].x); s.y = f2bf(bv[p].y); s.z = f2bf(bv[p].z); s.w = f2bf(bv[p].w);
      *(short4*)(&Bs[(p*32 + trow)*SK + tcol]) = s;
    }
    __syncthreads();
    bf16x8 af[TM], bfr[TN];
    #pragma unroll
    for (int i = 0; i < TM; i++)
      af[i] = *(const bf16x8*)(&As[(wm + i*16 + lm)*SK + q*8]);
    #pragma unroll
    for (int j = 0; j < TN; j++)
      bfr[j] = *(const bf16x8*)(&Bs[(wn + j*16 + lm)*SK + q*8]);
    #pragma unroll
    for (int i = 0; i < TM; i++)
      #pragma unroll
      for (int j = 0; j < TN; j++)
        acc[i][j] = __builtin_amdgcn_mfma_f32_16x16x32_bf16(af[i], bfr[j], acc[i][j], 0, 0, 0);
  }
  // epilogue: C/D layout col = lane&15, row = (lane>>4)*4 + reg
  #pragma unroll
  for (int i = 0; i < TM; i++) {
    #pragma unroll
    for (int j = 0; j < TN; j++) {
      int rm = m0 + wm + i*16 + q*4;
      int cn = n0 + wn + j*16 + lm;
      if (cn < N) {
        float* cp = C + (size_t)rm*N + cn;
        #pragma unroll
        for (int r2 = 0; r2 < 4; r2++) {
          float v = acc[i][j][r2];
          if (RES) v += cp[(size_t)r2*N];
          cp[(size_t)r2*N] = v;
        }
      }
    }
  }
}

// ---------------- causal depthwise conv (K=4) + bias + silu ----------------
__global__ __launch_bounds__(256) void k_conv(const float* __restrict__ xz,
                                              const float* __restrict__ cw,
                                              const float* __restrict__ cb,
                                              float* __restrict__ xs) {
  int idx = blockIdx.x * 256 + threadIdx.x;      // over 2*512*1536
  int d = idx % DI;
  int t = (idx / DI) % LQ;
  int b = idx / (DI * LQ);
  const float* xcol = xz + (size_t)b * LQ * (2*DI) + d;   // x[b,:,d], stride 3072
  float acc = cb[d];
  #pragma unroll
  for (int k = 0; k < 4; k++) {
    int tt = t + k - 3;
    if (tt >= 0) acc += cw[d*4 + k] * xcol[(size_t)tt * (2*DI)];
  }
  float s = acc / (1.0f + expf(-acc));   // silu
  xs[idx] = s;
}

// ---------------- x_proj: proj[m, 0:80] = xs[m,:] . w[n,:] ----------------
__global__ __launch_bounds__(256) void k_proj(const float* __restrict__ xs,
                                              const float* __restrict__ w,
                                              float* __restrict__ proj) {
  int wave = threadIdx.x >> 6, lane = threadIdx.x & 63;
  int m = blockIdx.x * 4 + wave;                 // one row per wave
  const float* xr = xs + (size_t)m * DI;
  float xv[24];
  #pragma unroll
  for (int j = 0; j < 24; j++) xv[j] = xr[lane + j*64];
  for (int n = 0; n < 80; n++) {
    const float* wr = w + (size_t)n * DI;
    float acc = 0.f;
    #pragma unroll
    for (int j = 0; j < 24; j++) acc += xv[j] * wr[lane + j*64];
    #pragma unroll
    for (int o = 32; o > 0; o >>= 1) acc += __shfl_xor(acc, o);
    if (lane == 0) proj[(size_t)m * 80 + n] = acc;
  }
}

// ---------------- dt = softplus(dt_r @ dtw^T + dtb) ----------------
__global__ __launch_bounds__(256) void k_dt(const float* __restrict__ proj,
                                            const float* __restrict__ dtw,
                                            const float* __restrict__ dtb,
                                            float* __restrict__ dt) {
  int m = blockIdx.y;
  int d = blockIdx.x * 256 + threadIdx.x;
  __shared__ float p[RK];
  if (threadIdx.x < RK) p[threadIdx.x] = proj[(size_t)m * 80 + threadIdx.x];
  __syncthreads();
  const float* wr = dtw + (size_t)d * RK;
  float acc = dtb[d];
  #pragma unroll
  for (int r = 0; r < RK; r++) acc += p[r] * wr[r];
  float sp = (acc > 20.f) ? acc : log1pf(expf(acc));
  dt[(size_t)m * DI + d] = sp;
}

// ---------------- chunked selective scan ----------------
// One block per (b,d). Thread (c,n): c = chunk (16 chunks of 32 steps), n = state.
// Pass 1: batched register preload + per-chunk carry (P = prod a, H = local state).
// Pass 2: 16-wide exclusive carry scan in LDS.
// Pass 3: register replay; writes yraw[t] = sum_n h_t[n]*C_t[n].
#define SCT 32   // chunk length
__global__ __launch_bounds__(256) void k_scan(const float* __restrict__ dt,
                                              const float* __restrict__ proj,
                                              const float* __restrict__ xs,
                                              const float* __restrict__ A_log,
                                              float* __restrict__ y) {
  const int d = blockIdx.x;        // 0..1535
  const int b = blockIdx.y;        // 0..1
  const int tid = threadIdx.x;
  const int n = tid & 15;
  const int c = tid >> 4;          // 0..15
  const int t0 = c * SCT;
  const float negA = -expf(A_log[d * NS + n]);
  const float* dtp = dt   + (size_t)b * LQ * DI + d;
  const float* xp  = xs   + (size_t)b * LQ * DI + d;
  const float* Bp  = proj + (size_t)b * LQ * 80 + RK + n;
  const float* Cp  = proj + (size_t)b * LQ * 80 + RK + NS + n;

  float a[SCT], u[SCT], Cv[SCT];
  #pragma unroll
  for (int j = 0; j < SCT; j++) {
    int t = t0 + j;
    float dtv = dtp[(size_t)t * DI];
    float xv  = xp[(size_t)t * DI];
    float Bv  = Bp[(size_t)t * 80];
    Cv[j]     = Cp[(size_t)t * 80];
    a[j] = expf(dtv * negA);
    u[j] = dtv * Bv * xv;
  }
  // per-chunk carry
  float P = 1.f, H = 0.f;
  #pragma unroll
  for (int j = 0; j < SCT; j++) { H = a[j]*H + u[j]; P *= a[j]; }

  __shared__ float Ps[16][16], Hs[16][16], Ss[16][16];
  Ps[c][n] = P; Hs[c][n] = H;
  __syncthreads();
  if (tid < 16) {          // lane nn scans its 16 chunk carries serially
    float S = 0.f;
    #pragma unroll
    for (int cc = 0; cc < 16; cc++) {
      Ss[cc][tid] = S;
      S = Ps[cc][tid] * S + Hs[cc][tid];
    }
  }
  __syncthreads();

  float h = Ss[c][n];
  float* yp = y + (size_t)b * LQ * DI + d;
  #pragma unroll
  for (int j = 0; j < SCT; j++) {
    h = a[j]*h + u[j];
    float yy = h * Cv[j];
    yy += __shfl_xor(yy, 1);
    yy += __shfl_xor(yy, 2);
    yy += __shfl_xor(yy, 4);
    yy += __shfl_xor(yy, 8);
    if (n == 0) yp[(size_t)(t0 + j) * DI] = yy;
  }
}

// ---------------- y = (yraw + Dp*x) * silu(z) ----------------
__global__ __launch_bounds__(256) void k_gate(float* __restrict__ y,
                                              const float* __restrict__ xs,
                                              const float* __restrict__ xz,
                                              const float* __restrict__ Dp) {
  int idx = blockIdx.x * 256 + threadIdx.x;   // over 2*512*1536
  int d = idx % DI;
  int bt = idx / DI;                          // b*512 + t
  float zv = xz[(size_t)bt * (2*DI) + DI + d];
  float sz = zv / (1.0f + expf(-zv));
  y[idx] = (y[idx] + Dp[d] * xs[idx]) * sz;
}

extern "C" void kernel_launch(void* const* d_in, const int* in_sizes, int n_in,
                              void* d_out, int out_size, void* d_ws, size_t ws_size,
                              hipStream_t stream) {
  const int*   q_ids        = (const int*)d_in[0];
  const int*   q_mask       = (const int*)d_in[1];
  const float* embed        = (const float*)d_in[4];
  const float* in_proj_w    = (const float*)d_in[5];
  const float* conv_w       = (const float*)d_in[6];
  const float* conv_b       = (const float*)d_in[7];
  const float* x_proj_w     = (const float*)d_in[8];
  const float* dt_proj_w    = (const float*)d_in[9];
  const float* dt_proj_b    = (const float*)d_in[10];
  const float* A_log        = (const float*)d_in[11];
  const float* Dp           = (const float*)d_in[12];
  const float* out_proj_w   = (const float*)d_in[13];
  const float* norm_w       = (const float*)d_in[14];
  const float* final_norm_w = (const float*)d_in[15];
  float* out = (float*)d_out;

  // workspace layout (floats)
  float* ws = (float*)d_ws;
  float* h   = ws;                    // 1024*768
  float* r   = h  + 786432;           // 1024*768
  float* xz  = r  + 786432;           // 1024*3072
  float* xs  = xz + 3145728;          // 1024*1536
  float* pj  = xs + 1572864;          // 1024*80
  float* dtb = pj + 81920;            // 1024*1536
  float* y   = dtb + 1572864;         // 1024*1536

  k_gather<<<MROWS, 256, 0, stream>>>(q_ids, q_mask, embed, h);

  for (int l = 0; l < 4; l++) {
    k_rmsnorm<<<MROWS, 256, 0, stream>>>(h, norm_w + (size_t)l*DM, r);
    // xz = r @ in_proj_w[l]^T : M=1024 N=3072 K=768 (64x128 tiles)
    k_gemm_nt<2,4,false><<<dim3(3072/128, MROWS/64), 256, 0, stream>>>(
        r, in_proj_w + (size_t)l*2*DI*DM, xz, MROWS, 2*DI, DM);
    k_conv<<<(MROWS*DI)/256, 256, 0, stream>>>(xz, conv_w + (size_t)l*DI*4,
                                               conv_b + (size_t)l*DI, xs);
    k_proj<<<MROWS/4, 256, 0, stream>>>(xs, x_proj_w + (size_t)l*80*DI, pj);
    k_dt<<<dim3(DI/256, MROWS), 256, 0, stream>>>(pj, dt_proj_w + (size_t)l*DI*RK,
                                                  dt_proj_b + (size_t)l*DI, dtb);
    k_scan<<<dim3(DI, BB), 256, 0, stream>>>(dtb, pj, xs,
                                             A_log + (size_t)l*DI*NS, y);
    k_gate<<<(MROWS*DI)/256, 256, 0, stream>>>(y, xs, xz, Dp + (size_t)l*DI);
    // h += y @ out_proj_w[l]^T : M=1024 N=768 K=1536 (64x64 tiles)
    k_gemm_nt<2,2,true><<<dim3(DM/64, MROWS/64), 256, 0, stream>>>(
        y, out_proj_w + (size_t)l*DM*DI, h, MROWS, DM, DI);
  }

  k_rmsnorm<<<MROWS, 256, 0, stream>>>(h, final_norm_w, r);
  // logits = r @ embed^T : M=1024 N=50280 K=768 (128x128 tiles)
  k_gemm_nt<4,4,false><<<dim3((50280 + 127)/128, MROWS/128), 256, 0, stream>>>(
      r, embed, out, MROWS, 50280, 768);
}

// Round 2
// 1537.053 us; speedup vs baseline: 1.0895x; 1.0895x over previous
//
#include <hip/hip_runtime.h>

// Problem constants
#define DI 1536
#define DM 768
#define NS 16
#define RK 48
#define LQ 512
#define BB 2
#define MROWS (BB*LQ)   // 1024

typedef unsigned short u16;
typedef short bf16x8 __attribute__((ext_vector_type(8)));
typedef float f32x4 __attribute__((ext_vector_type(4)));
typedef u16 u16x8 __attribute__((ext_vector_type(8)));

static __device__ __forceinline__ short f2bf(float f) {
  unsigned u = __float_as_uint(f);
  u += 0x7FFF + ((u >> 16) & 1);   // round-to-nearest-even
  return (short)(u >> 16);
}

// async global->LDS, 16B per lane. LDS dest = wave-uniform base + lane*16.
static __device__ __forceinline__ void gld16(const void* g, void* l) {
  __builtin_amdgcn_global_load_lds((const __attribute__((address_space(1))) unsigned int*)g,
                                   (__attribute__((address_space(3))) unsigned int*)l,
                                   16, 0, 0);
}

// ---------------- fp32 -> bf16 cast (n multiple of 8) ----------------
__global__ __launch_bounds__(256) void k_cast8(const float* __restrict__ s,
                                               u16* __restrict__ d, long n) {
  long i = ((long)blockIdx.x * 256 + threadIdx.x) * 8;
  if (i >= n) return;
  float4 a = *(const float4*)(s + i);
  float4 b = *(const float4*)(s + i + 4);
  u16x8 o;
  o[0] = (u16)f2bf(a.x); o[1] = (u16)f2bf(a.y); o[2] = (u16)f2bf(a.z); o[3] = (u16)f2bf(a.w);
  o[4] = (u16)f2bf(b.x); o[5] = (u16)f2bf(b.y); o[6] = (u16)f2bf(b.z); o[7] = (u16)f2bf(b.w);
  *(u16x8*)(d + i) = o;
}

// ---------------- embedding gather ----------------
__global__ __launch_bounds__(256) void k_gather(const int* __restrict__ ids,
                                                const int* __restrict__ mask,
                                                const float* __restrict__ embed,
                                                float* __restrict__ h) {
  int row = blockIdx.x;                 // 0..1023 = b*512 + l
  int id = ids[row];
  float mk = (float)mask[row];
  const float* src = embed + (size_t)id * DM;
  float* dst = h + (size_t)row * DM;
  for (int i = threadIdx.x; i < DM; i += 256) dst[i] = src[i] * mk;
}

// ---------------- rmsnorm (768 per row) -> bf16 out ----------------
__global__ __launch_bounds__(256) void k_rmsnorm(const float* __restrict__ h,
                                                 const float* __restrict__ w,
                                                 u16* __restrict__ out) {
  int row = blockIdx.x;
  const float* x = h + (size_t)row * DM;
  int tid = threadIdx.x;
  float v0 = x[tid], v1 = x[tid + 256], v2 = x[tid + 512];
  float ss = v0*v0 + v1*v1 + v2*v2;
  #pragma unroll
  for (int o = 32; o > 0; o >>= 1) ss += __shfl_xor(ss, o);
  __shared__ float ps[4];
  if ((tid & 63) == 0) ps[tid >> 6] = ss;
  __syncthreads();
  float tot = ps[0] + ps[1] + ps[2] + ps[3];
  float scale = rsqrtf(tot * (1.0f/768.0f) + 1e-5f);
  u16* o0 = out + (size_t)row * DM;
  o0[tid]       = (u16)f2bf(v0 * scale * w[tid]);
  o0[tid + 256] = (u16)f2bf(v1 * scale * w[tid + 256]);
  o0[tid + 512] = (u16)f2bf(v2 * scale * w[tid + 512]);
}

// ---------------- bf16 MFMA GEMM: C[m,n] = sum_k A[m,k]*B[n,k] (+C) ----------------
// A: M x K row-major bf16 (M multiple of BM), B: N x K row-major bf16 (tail clamped),
// C: M x N fp32. Staging via global_load_lds (16B/lane) into linear LDS [rows][32].
// XCD swizzle: the RT row-readers of one B column-tile get consecutive dispatch slots
// with the same lin%8 => same XCD => B filled into exactly one L2.
template<int WM, int WN, int TM, int TN, bool RES>
__global__ __launch_bounds__(256) void k_gemm_bf(const u16* __restrict__ A,
                                                 const u16* __restrict__ B,
                                                 float* __restrict__ C,
                                                 int M, int N, int K) {
  constexpr int BM = WM*TM*16, BN = WN*TN*16, BK = 32;
  __shared__ __attribute__((aligned(16))) u16 As[BM*BK];
  __shared__ __attribute__((aligned(16))) u16 Bs[BN*BK];

  // ---- XCD-aware bijective remap ----
  int bx, by;
  {
    int CT = gridDim.x, RT = gridDim.y;
    int lin = blockIdx.y * CT + blockIdx.x;   // dispatch order: x fastest
    int CT8 = CT & ~7;
    int main_n = CT8 * RT;
    if (lin < main_n) {
      int x = lin & 7, g = lin >> 3;          // x = XCD slot
      by = g % RT;
      bx = x + 8 * (g / RT);                  // each XCD walks cols x, x+8, ...
    } else {
      int rem = lin - main_n;
      by = rem % RT;
      bx = CT8 + rem / RT;
    }
  }

  const int m0 = by * BM, n0 = bx * BN;
  const int tid = threadIdx.x;
  const int wave = tid >> 6, lane = tid & 63;
  const int wm = (wave / WN) * (TM*16), wn = (wave % WN) * (TN*16);
  const int lm = lane & 15, q = lane >> 4;
  const int srow = tid >> 2;          // 0..63 (staging row within 64-row group)
  const int ssub = (tid & 3) * 8;     // k-offset in elements (16B granules)

  f32x4 acc[TM][TN] = {};
  for (int kt = 0; kt < K; kt += BK) {
    __syncthreads();   // previous iteration's LDS reads done
    #pragma unroll
    for (int i = 0; i < BM/64; i++) {
      const u16* g = A + (size_t)(m0 + i*64 + srow)*K + kt + ssub;
      gld16(g, (void*)(As + (i*256 + wave*64)*8));
    }
    #pragma unroll
    for (int i = 0; i < BN/64; i++) {
      int bn = n0 + i*64 + srow;
      if (bn > N-1) bn = N-1;                 // clamp tail (logits): garbage cols masked at C-write
      const u16* g = B + (size_t)bn*K + kt + ssub;
      gld16(g, (void*)(Bs + (i*256 + wave*64)*8));
    }
    __syncthreads();   // staged tile visible (compiler drains vmcnt before barrier)
    bf16x8 af[TM], bfr[TN];
    #pragma unroll
    for (int i = 0; i < TM; i++)
      af[i] = *(const bf16x8*)(&As[(wm + i*16 + lm)*BK + q*8]);
    #pragma unroll
    for (int j = 0; j < TN; j++)
      bfr[j] = *(const bf16x8*)(&Bs[(wn + j*16 + lm)*BK + q*8]);
    #pragma unroll
    for (int i = 0; i < TM; i++)
      #pragma unroll
      for (int j = 0; j < TN; j++)
        acc[i][j] = __builtin_amdgcn_mfma_f32_16x16x32_bf16(af[i], bfr[j], acc[i][j], 0, 0, 0);
  }
  // epilogue: C/D layout col = lane&15, row = (lane>>4)*4 + reg
  #pragma unroll
  for (int i = 0; i < TM; i++) {
    #pragma unroll
    for (int j = 0; j < TN; j++) {
      int rm = m0 + wm + i*16 + q*4;
      int cn = n0 + wn + j*16 + lm;
      if (cn < N) {
        float* cp = C + (size_t)rm*N + cn;
        #pragma unroll
        for (int r2 = 0; r2 < 4; r2++) {
          float v = acc[i][j][r2];
          if (RES) v += cp[(size_t)r2*N];
          cp[(size_t)r2*N] = v;
        }
      }
    }
  }
}

// ---------------- causal depthwise conv (K=4) + bias + silu ----------------
__global__ __launch_bounds__(256) void k_conv(const float* __restrict__ xz,
                                              const float* __restrict__ cw,
                                              const float* __restrict__ cb,
                                              float* __restrict__ xs) {
  int idx = blockIdx.x * 256 + threadIdx.x;      // over 2*512*1536
  int d = idx % DI;
  int t = (idx / DI) % LQ;
  int b = idx / (DI * LQ);
  const float* xcol = xz + (size_t)b * LQ * (2*DI) + d;   // x[b,:,d], stride 3072
  float acc = cb[d];
  #pragma unroll
  for (int k = 0; k < 4; k++) {
    int tt = t + k - 3;
    if (tt >= 0) acc += cw[d*4 + k] * xcol[(size_t)tt * (2*DI)];
  }
  float s = acc / (1.0f + expf(-acc));   // silu
  xs[idx] = s;
}

// ---------------- x_proj: proj[m, 0:80] = xs[m,:] . w[n,:] ----------------
__global__ __launch_bounds__(256) void k_proj(const float* __restrict__ xs,
                                              const float* __restrict__ w,
                                              float* __restrict__ proj) {
  int wave = threadIdx.x >> 6, lane = threadIdx.x & 63;
  int m = blockIdx.x * 4 + wave;                 // one row per wave
  const float* xr = xs + (size_t)m * DI;
  float xv[24];
  #pragma unroll
  for (int j = 0; j < 24; j++) xv[j] = xr[lane + j*64];
  for (int n = 0; n < 80; n++) {
    const float* wr = w + (size_t)n * DI;
    float acc = 0.f;
    #pragma unroll
    for (int j = 0; j < 24; j++) acc += xv[j] * wr[lane + j*64];
    #pragma unroll
    for (int o = 32; o > 0; o >>= 1) acc += __shfl_xor(acc, o);
    if (lane == 0) proj[(size_t)m * 80 + n] = acc;
  }
}

// ---------------- dt = softplus(dt_r @ dtw^T + dtb) ----------------
__global__ __launch_bounds__(256) void k_dt(const float* __restrict__ proj,
                                            const float* __restrict__ dtw,
                                            const float* __restrict__ dtb,
                                            float* __restrict__ dt) {
  int m = blockIdx.y;
  int d = blockIdx.x * 256 + threadIdx.x;
  __shared__ float p[RK];
  if (threadIdx.x < RK) p[threadIdx.x] = proj[(size_t)m * 80 + threadIdx.x];
  __syncthreads();
  const float* wr = dtw + (size_t)d * RK;
  float acc = dtb[d];
  #pragma unroll
  for (int r = 0; r < RK; r++) acc += p[r] * wr[r];
  float sp = (acc > 20.f) ? acc : log1pf(expf(acc));
  dt[(size_t)m * DI + d] = sp;
}

// ---------------- chunked selective scan ----------------
#define SCT 32   // chunk length
__global__ __launch_bounds__(256) void k_scan(const float* __restrict__ dt,
                                              const float* __restrict__ proj,
                                              const float* __restrict__ xs,
                                              const float* __restrict__ A_log,
                                              float* __restrict__ y) {
  const int d = blockIdx.x;        // 0..1535
  const int b = blockIdx.y;        // 0..1
  const int tid = threadIdx.x;
  const int n = tid & 15;
  const int c = tid >> 4;          // 0..15
  const int t0 = c * SCT;
  const float negA = -expf(A_log[d * NS + n]);
  const float* dtp = dt   + (size_t)b * LQ * DI + d;
  const float* xp  = xs   + (size_t)b * LQ * DI + d;
  const float* Bp  = proj + (size_t)b * LQ * 80 + RK + n;
  const float* Cp  = proj + (size_t)b * LQ * 80 + RK + NS + n;

  float a[SCT], u[SCT], Cv[SCT];
  #pragma unroll
  for (int j = 0; j < SCT; j++) {
    int t = t0 + j;
    float dtv = dtp[(size_t)t * DI];
    float xv  = xp[(size_t)t * DI];
    float Bv  = Bp[(size_t)t * 80];
    Cv[j]     = Cp[(size_t)t * 80];
    a[j] = expf(dtv * negA);
    u[j] = dtv * Bv * xv;
  }
  // per-chunk carry
  float P = 1.f, H = 0.f;
  #pragma unroll
  for (int j = 0; j < SCT; j++) { H = a[j]*H + u[j]; P *= a[j]; }

  __shared__ float Ps[16][16], Hs[16][16], Ss[16][16];
  Ps[c][n] = P; Hs[c][n] = H;
  __syncthreads();
  if (tid < 16) {          // lane nn scans its 16 chunk carries serially
    float S = 0.f;
    #pragma unroll
    for (int cc = 0; cc < 16; cc++) {
      Ss[cc][tid] = S;
      S = Ps[cc][tid] * S + Hs[cc][tid];
    }
  }
  __syncthreads();

  float h = Ss[c][n];
  float* yp = y + (size_t)b * LQ * DI + d;
  #pragma unroll
  for (int j = 0; j < SCT; j++) {
    h = a[j]*h + u[j];
    float yy = h * Cv[j];
    yy += __shfl_xor(yy, 1);
    yy += __shfl_xor(yy, 2);
    yy += __shfl_xor(yy, 4);
    yy += __shfl_xor(yy, 8);
    if (n == 0) yp[(size_t)(t0 + j) * DI] = yy;
  }
}

// ---------------- y = (yraw + Dp*x) * silu(z) -> bf16 ----------------
__global__ __launch_bounds__(256) void k_gate(const float* __restrict__ y,
                                              const float* __restrict__ xs,
                                              const float* __restrict__ xz,
                                              const float* __restrict__ Dp,
                                              u16* __restrict__ yb) {
  int idx = blockIdx.x * 256 + threadIdx.x;   // over 2*512*1536
  int d = idx % DI;
  int bt = idx / DI;                          // b*512 + t
  float zv = xz[(size_t)bt * (2*DI) + DI + d];
  float sz = zv / (1.0f + expf(-zv));
  float v = (y[idx] + Dp[d] * xs[idx]) * sz;
  yb[idx] = (u16)f2bf(v);
}

extern "C" void kernel_launch(void* const* d_in, const int* in_sizes, int n_in,
                              void* d_out, int out_size, void* d_ws, size_t ws_size,
                              hipStream_t stream) {
  const int*   q_ids        = (const int*)d_in[0];
  const int*   q_mask       = (const int*)d_in[1];
  const float* embed        = (const float*)d_in[4];
  const float* in_proj_w    = (const float*)d_in[5];
  const float* conv_w       = (const float*)d_in[6];
  const float* conv_b       = (const float*)d_in[7];
  const float* x_proj_w     = (const float*)d_in[8];
  const float* dt_proj_w    = (const float*)d_in[9];
  const float* dt_proj_b    = (const float*)d_in[10];
  const float* A_log        = (const float*)d_in[11];
  const float* Dp           = (const float*)d_in[12];
  const float* out_proj_w   = (const float*)d_in[13];
  const float* norm_w       = (const float*)d_in[14];
  const float* final_norm_w = (const float*)d_in[15];
  float* out = (float*)d_out;

  // workspace layout
  float* ws = (float*)d_ws;
  float* h   = ws;                    // 1024*768
  float* xz  = h  + 786432;           // 1024*3072
  float* xs  = xz + 3145728;          // 1024*1536
  float* pj  = xs + 1572864;          // 1024*80
  float* dtb = pj + 81920;            // 1024*1536
  float* y   = dtb + 1572864;         // 1024*1536
  u16*   rb  = (u16*)(y + 1572864);   // 1024*768  bf16
  u16*   yb  = rb  + 786432;          // 1024*1536 bf16
  u16*   ipw = yb  + 1572864;         // 4*3072*768 bf16
  u16*   opw = ipw + 9437184;         // 4*768*1536 bf16
  u16*   emb = opw + 4718592;         // 50280*768  bf16

  // one-time (per call) weight casts
  k_cast8<<<4608, 256, 0, stream>>>(in_proj_w, ipw, 9437184L);
  k_cast8<<<2304, 256, 0, stream>>>(out_proj_w, opw, 4718592L);
  k_cast8<<<18855, 256, 0, stream>>>(embed, emb, 38615040L);

  k_gather<<<MROWS, 256, 0, stream>>>(q_ids, q_mask, embed, h);

  for (int l = 0; l < 4; l++) {
    k_rmsnorm<<<MROWS, 256, 0, stream>>>(h, norm_w + (size_t)l*DM, rb);
    // xz = r @ in_proj_w[l]^T : M=1024 N=3072 K=768 (64x128 tiles)
    k_gemm_bf<1,4,4,2,false><<<dim3(3072/128, MROWS/64), 256, 0, stream>>>(
        rb, ipw + (size_t)l*2359296, xz, MROWS, 2*DI, DM);
    k_conv<<<(MROWS*DI)/256, 256, 0, stream>>>(xz, conv_w + (size_t)l*DI*4,
                                               conv_b + (size_t)l*DI, xs);
    k_proj<<<MROWS/4, 256, 0, stream>>>(xs, x_proj_w + (size_t)l*80*DI, pj);
    k_dt<<<dim3(DI/256, MROWS), 256, 0, stream>>>(pj, dt_proj_w + (size_t)l*DI*RK,
                                                  dt_proj_b + (size_t)l*DI, dtb);
    k_scan<<<dim3(DI, BB), 256, 0, stream>>>(dtb, pj, xs,
                                             A_log + (size_t)l*DI*NS, y);
    k_gate<<<(MROWS*DI)/256, 256, 0, stream>>>(y, xs, xz, Dp + (size_t)l*DI, yb);
    // h += y @ out_proj_w[l]^T : M=1024 N=768 K=1536 (64x64 tiles)
    k_gemm_bf<2,2,2,2,true><<<dim3(DM/64, MROWS/64), 256, 0, stream>>>(
        yb, opw + (size_t)l*1179648, h, MROWS, DM, DI);
  }

  k_rmsnorm<<<MROWS, 256, 0, stream>>>(h, final_norm_w, rb);
  // logits = r @ embed^T : M=1024 N=50280 K=768 (128x128 tiles)
  k_gemm_bf<2,2,4,4,false><<<dim3((50280 + 127)/128, MROWS/128), 256, 0, stream>>>(
      rb, emb, out, MROWS, 50280, 768);
}